// Round 14
// baseline (187.429 us; speedup 1.0000x reference)
//
#include <hip/hip_runtime.h>

typedef __attribute__((ext_vector_type(8))) short bf16x8;
typedef __attribute__((ext_vector_type(4))) float f32x4;

constexpr int NN = 50000;          // nodes
constexpr int NE = 800000;         // edges
constexpr int C1 = 128;            // in/hidden channels
constexpr int C2 = 64;             // out channels
constexpr int NBK = 196;           // dst buckets of 256 nodes
constexpr int EPB = 2048;          // edges per bin block
constexpr int NBLK = (NE + EPB - 1) / EPB;   // 391
constexpr int MT = NN / 16;        // 3125 M-tiles (exact)
constexpr int MMB = 250;           // matmul blocks
constexpr int MMWAVES = MMB * 4;   // 1000 waves
constexpr int CAP = 8192;          // LDS edge cache per bucket
constexpr int GNB = (NN + 63) / 64;   // 782 gather node-blocks (64 nodes each)

// float -> bf16 round-to-nearest-even
__device__ __forceinline__ unsigned short f2bf(float f) {
    unsigned int u = __float_as_uint(f);
    u += 0x7FFFu + ((u >> 16) & 1u);
    return (unsigned short)(u >> 16);
}
// packed bf16 pair -> two floats (low ushort = even element)
__device__ __forceinline__ float2 bf2f(unsigned int u) {
    return make_float2(__uint_as_float(u << 16), __uint_as_float(u & 0xFFFF0000u));
}
__device__ __forceinline__ bf16x8 pack8(float4 a, float4 b) {
    bf16x8 r;
    r[0] = (short)f2bf(a.x); r[1] = (short)f2bf(a.y);
    r[2] = (short)f2bf(a.z); r[3] = (short)f2bf(a.w);
    r[4] = (short)f2bf(b.x); r[5] = (short)f2bf(b.y);
    r[6] = (short)f2bf(b.z); r[7] = (short)f2bf(b.w);
    return r;
}
// accumulate 8 packed bf16 (uint4) into 8 fp32
__device__ __forceinline__ void addrow(float* a, uint4 v) {
    float2 p;
    p = bf2f(v.x); a[0] += p.x; a[1] += p.y;
    p = bf2f(v.y); a[2] += p.x; a[3] += p.y;
    p = bf2f(v.z); a[4] += p.x; a[5] += p.y;
    p = bf2f(v.w); a[6] += p.x; a[7] += p.y;
}

// ---------------- CSR build pass 1: per-block counting sort by coarse bucket ----------------
__global__ __launch_bounds__(256) void bin_kernel(const int* __restrict__ src,
                                                  const int* __restrict__ dst,
                                                  unsigned int* __restrict__ ebuf,
                                                  int* __restrict__ localOff) {
    __shared__ int lhist[NBK];
    __shared__ int ls[256];
    __shared__ int lcur[NBK];
    __shared__ unsigned int lbuf[EPB];
    const int t = threadIdx.x;
    const int base = blockIdx.x * EPB;
    if (t < NBK) lhist[t] = 0;
    __syncthreads();
    int b[8]; unsigned int p[8];
    #pragma unroll
    for (int i = 0; i < 8; i++) {
        int e = base + i * 256 + t;
        if (e < NE) {
            int s = src[e], d = dst[e];
            b[i] = d >> 8;
            p[i] = ((unsigned int)(d & 255) << 16) | (unsigned int)s;
            atomicAdd(&lhist[b[i]], 1);
        } else b[i] = -1;
    }
    __syncthreads();
    int v = (t < NBK) ? lhist[t] : 0;
    ls[t] = v;
    __syncthreads();
    #pragma unroll
    for (int d = 1; d < 256; d <<= 1) {
        int u = (t >= d) ? ls[t - d] : 0;
        __syncthreads();
        ls[t] += u;
        __syncthreads();
    }
    if (t < NBK) {
        lcur[t] = ls[t] - v;
        localOff[blockIdx.x * 200 + t] = ls[t] - v;
    }
    if (t == NBK - 1) localOff[blockIdx.x * 200 + NBK] = ls[t];
    __syncthreads();
    #pragma unroll
    for (int i = 0; i < 8; i++) {
        if (b[i] >= 0) {
            int lp = atomicAdd(&lcur[b[i]], 1);
            lbuf[lp] = p[i];
        }
    }
    __syncthreads();
    #pragma unroll
    for (int i = 0; i < 8; i++)
        ebuf[base + i * 256 + t] = lbuf[i * 256 + t];   // tail garbage never read
}

// ---------------- CSR build pass 2: one block per bucket, bucket edges cached in LDS ---------
__global__ __launch_bounds__(256) void place_kernel(const unsigned int* __restrict__ ebuf,
                                                    const int* __restrict__ localOff,
                                                    unsigned short* __restrict__ esrc,
                                                    int* __restrict__ cnt,
                                                    int* __restrict__ off,
                                                    float* __restrict__ dinv) {
    __shared__ unsigned int lbuf[CAP];   // 32 KB
    __shared__ int lhist[256];
    __shared__ int ls[256];
    __shared__ int lcur[256];
    __shared__ int red[256];
    const int t = threadIdx.x;
    const int bkt = blockIdx.x;
    const int node0 = bkt << 8;
    const int nnodes = min(256, NN - node0);

    const int j0 = 2 * t, j1 = 2 * t + 1;
    int s0 = 0, l0 = 0, s1 = 0, l1 = 0;
    if (j0 < NBLK) { s0 = localOff[j0 * 200 + bkt]; l0 = localOff[j0 * 200 + bkt + 1] - s0; }
    if (j1 < NBLK) { s1 = localOff[j1 * 200 + bkt]; l1 = localOff[j1 * 200 + bkt + 1] - s1; }

    red[t] = s0 + s1;          // -> segBase (sum of chunk-local exclusive prefixes)
    ls[t] = l0 + l1;           // -> lbuf base scan
    lhist[t] = 0;
    __syncthreads();
    #pragma unroll
    for (int d = 1; d < 256; d <<= 1) {
        int u = (t >= d) ? ls[t - d] : 0;
        int r = (t + d < 256) ? red[t + d] : 0;
        __syncthreads();
        ls[t] += u;
        red[t] += r;
        __syncthreads();
    }
    const int segBase = red[0];
    const int total = ls[255];
    const int base0 = ls[t] - (l0 + l1);
    const int base1 = base0 + l0;
    const bool fits = (total <= CAP);

    if (fits) {
        const unsigned int* q0 = ebuf + j0 * EPB + s0;
        for (int k = 0; k < l0; k++) lbuf[base0 + k] = q0[k];
        const unsigned int* q1 = ebuf + j1 * EPB + s1;
        for (int k = 0; k < l1; k++) lbuf[base1 + k] = q1[k];
        __syncthreads();
        for (int k = t; k < total; k += 256) atomicAdd(&lhist[lbuf[k] >> 16], 1);
    } else {
        const unsigned int* q0 = ebuf + j0 * EPB + s0;
        for (int k = 0; k < l0; k++) atomicAdd(&lhist[q0[k] >> 16], 1);
        const unsigned int* q1 = ebuf + j1 * EPB + s1;
        for (int k = 0; k < l1; k++) atomicAdd(&lhist[q1[k] >> 16], 1);
    }
    __syncthreads();
    int v = lhist[t];
    ls[t] = v;
    __syncthreads();
    #pragma unroll
    for (int d = 1; d < 256; d <<= 1) {
        int u = (t >= d) ? ls[t - d] : 0;
        __syncthreads();
        ls[t] += u;
        __syncthreads();
    }
    int ex = ls[t] - v;
    lcur[t] = ex;
    if (t < nnodes) {
        cnt[node0 + t] = v;
        off[node0 + t] = segBase + ex;
        dinv[node0 + t] = rsqrtf((float)v + 1.0f);
    }
    __syncthreads();
    if (fits) {
        for (int k = t; k < total; k += 256) {
            unsigned int pp = lbuf[k];
            int lp = atomicAdd(&lcur[pp >> 16], 1);
            esrc[segBase + lp] = (unsigned short)(pp & 0xFFFFu);
        }
    } else {
        const unsigned int* q0 = ebuf + j0 * EPB + s0;
        for (int k = 0; k < l0; k++) {
            unsigned int pp = q0[k];
            int lp = atomicAdd(&lcur[pp >> 16], 1);
            esrc[segBase + lp] = (unsigned short)(pp & 0xFFFFu);
        }
        const unsigned int* q1 = ebuf + j1 * EPB + s1;
        for (int k = 0; k < l1; k++) {
            unsigned int pp = q1[k];
            int lp = atomicAdd(&lcur[pp >> 16], 1);
            esrc[segBase + lp] = (unsigned short)(pp & 0xFFFFu);
        }
    }
}

// ---------------- mm1: g1(bf16, row-major) = dinv * (x @ W1) via MFMA 16x16x32 bf16 ----------
__global__ __launch_bounds__(256, 2) void mm1_kernel(const float* __restrict__ x,
                                                     const float* __restrict__ W,
                                                     const float* __restrict__ dinv,
                                                     unsigned short* __restrict__ g1) {
    __shared__ unsigned short wl[4][8][64][8];   // 32 KB, B-fragment order
    const int t = threadIdx.x;
    for (int i = 0; i < 64; i++) {
        int idx = i * 256 + t;
        int k = idx >> 7, n = idx & 127;
        wl[k >> 5][n >> 4][((k >> 3) & 3) * 16 + (n & 15)][k & 7] = f2bf(W[idx]);
    }
    __syncthreads();
    const int lane = t & 63, lm = lane & 15, quad = lane >> 4;

    bf16x8 bfr[4][8];
    #pragma unroll
    for (int s = 0; s < 4; s++)
        #pragma unroll
        for (int nt = 0; nt < 8; nt++)
            bfr[s][nt] = *(const bf16x8*)&wl[s][nt][lane][0];

    int wg = blockIdx.x * 4 + (t >> 6);
    for (int tile = wg; tile < MT; tile += MMWAVES) {
        int row0 = tile << 4;
        const float* xr = x + (size_t)(row0 + lm) * 128 + quad * 8;
        bf16x8 af[4];
        #pragma unroll
        for (int s = 0; s < 4; s++) {
            float4 p = *(const float4*)(xr + s * 32);
            float4 q = *(const float4*)(xr + s * 32 + 4);
            af[s] = pack8(p, q);
        }
        f32x4 acc[8];
        #pragma unroll
        for (int nt = 0; nt < 8; nt++) acc[nt] = (f32x4){0.f, 0.f, 0.f, 0.f};
        #pragma unroll
        for (int s = 0; s < 4; s++)
            #pragma unroll
            for (int nt = 0; nt < 8; nt++)
                acc[nt] = __builtin_amdgcn_mfma_f32_16x16x32_bf16(af[s], bfr[s][nt],
                                                                  acc[nt], 0, 0, 0);
        float4 dv = *(const float4*)(dinv + row0 + quad * 4);
        float dvv[4] = {dv.x, dv.y, dv.z, dv.w};
        #pragma unroll
        for (int nt = 0; nt < 8; nt++)
            #pragma unroll
            for (int r = 0; r < 4; r++)
                g1[(size_t)(row0 + quad * 4 + r) * 128 + nt * 16 + lm] =
                    f2bf(acc[nt][r] * dvv[r]);
    }
}

// ---------------- mm2: g2(bf16, row-major) = dinv * (x2 @ W2), x2 already bf16 ---------------
__global__ __launch_bounds__(256, 2) void mm2_kernel(const unsigned short* __restrict__ x2,
                                                     const float* __restrict__ W,
                                                     const float* __restrict__ dinv,
                                                     unsigned short* __restrict__ g2) {
    __shared__ unsigned short wl[4][4][64][8];   // 16 KB
    const int t = threadIdx.x;
    for (int i = 0; i < 32; i++) {
        int idx = i * 256 + t;
        int k = idx >> 6, n = idx & 63;
        wl[k >> 5][n >> 4][((k >> 3) & 3) * 16 + (n & 15)][k & 7] = f2bf(W[idx]);
    }
    __syncthreads();
    const int lane = t & 63, lm = lane & 15, quad = lane >> 4;

    bf16x8 bfr[4][4];
    #pragma unroll
    for (int s = 0; s < 4; s++)
        #pragma unroll
        for (int nt = 0; nt < 4; nt++)
            bfr[s][nt] = *(const bf16x8*)&wl[s][nt][lane][0];

    int wg = blockIdx.x * 4 + (t >> 6);
    for (int tile = wg; tile < MT; tile += MMWAVES) {
        int row0 = tile << 4;
        const bf16x8* xr = (const bf16x8*)(x2 + (size_t)(row0 + lm) * 128 + quad * 8);
        bf16x8 af[4];
        #pragma unroll
        for (int s = 0; s < 4; s++) af[s] = xr[s * 4];
        f32x4 acc[4];
        #pragma unroll
        for (int nt = 0; nt < 4; nt++) acc[nt] = (f32x4){0.f, 0.f, 0.f, 0.f};
        #pragma unroll
        for (int s = 0; s < 4; s++)
            #pragma unroll
            for (int nt = 0; nt < 4; nt++)
                acc[nt] = __builtin_amdgcn_mfma_f32_16x16x32_bf16(af[s], bfr[s][nt],
                                                                  acc[nt], 0, 0, 0);
        float4 dv = *(const float4*)(dinv + row0 + quad * 4);
        float dvv[4] = {dv.x, dv.y, dv.z, dv.w};
        #pragma unroll
        for (int nt = 0; nt < 4; nt++)
            #pragma unroll
            for (int r = 0; r < 4; r++)
                g2[(size_t)(row0 + quad * 4 + r) * 64 + nt * 16 + lm] =
                    f2bf(acc[nt][r] * dvv[r]);
    }
}

// ---------------- gather1: XCD-pinned 64B slice, 4-lane group x uint4, unroll 4 --------------
// Row = 16 uint4. Group = 4 lanes, each owns one uint4 (8 ch); group owns (node, slice).
// slice = blockIdx&3 (b%8 XCD round-robin -> XCD x only touches slice x&3, 3.2 MB resident).
// 4 independent index loads then 4 independent row loads per iteration: 256 B in flight/group.
__global__ __launch_bounds__(256) void gather1_kernel(const unsigned short* __restrict__ g1,
                                                      const unsigned short* __restrict__ esrc,
                                                      const int* __restrict__ off,
                                                      const int* __restrict__ cnt,
                                                      const float* __restrict__ dinv,
                                                      const float* __restrict__ b1,
                                                      unsigned short* __restrict__ x2) {
    const int slice = blockIdx.x & 3;
    const int n = (blockIdx.x >> 2) * 64 + (threadIdx.x >> 2);
    if (n >= NN) return;
    const int p = threadIdx.x & 3;
    const int col = slice * 4 + p;               // uint4 col in [0,16)
    const uint4* G = (const uint4*)g1;           // row stride 16
    float a0[8] = {0,0,0,0,0,0,0,0};
    float a1[8] = {0,0,0,0,0,0,0,0};
    float a2[8] = {0,0,0,0,0,0,0,0};
    float a3[8] = {0,0,0,0,0,0,0,0};
    addrow(a0, G[(size_t)n * 16 + col]);         // self-loop (lane owns its 8 ch)
    int s0 = off[n], c = cnt[n];
    int i = 0;
    for (; i + 3 < c; i += 4) {
        int sA = esrc[s0 + i];
        int sB = esrc[s0 + i + 1];
        int sC = esrc[s0 + i + 2];
        int sD = esrc[s0 + i + 3];
        uint4 vA = G[(size_t)sA * 16 + col];
        uint4 vB = G[(size_t)sB * 16 + col];
        uint4 vC = G[(size_t)sC * 16 + col];
        uint4 vD = G[(size_t)sD * 16 + col];
        addrow(a0, vA);
        addrow(a1, vB);
        addrow(a2, vC);
        addrow(a3, vD);
    }
    for (; i < c; i++) addrow(a0, G[(size_t)esrc[s0 + i] * 16 + col]);
    #pragma unroll
    for (int j = 0; j < 8; j++) a0[j] += a1[j] + a2[j] + a3[j];
    float sc = dinv[n];
    float4 bA = ((const float4*)b1)[col * 2];
    float4 bB = ((const float4*)b1)[col * 2 + 1];
    float4 pp = make_float4(fmaxf(sc * a0[0] + bA.x, 0.f), fmaxf(sc * a0[1] + bA.y, 0.f),
                            fmaxf(sc * a0[2] + bA.z, 0.f), fmaxf(sc * a0[3] + bA.w, 0.f));
    float4 qq = make_float4(fmaxf(sc * a0[4] + bB.x, 0.f), fmaxf(sc * a0[5] + bB.y, 0.f),
                            fmaxf(sc * a0[6] + bB.z, 0.f), fmaxf(sc * a0[7] + bB.w, 0.f));
    *(bf16x8*)(x2 + (size_t)n * 128 + col * 8) = pack8(pp, qq);
}

// ---------------- gather2: same, 2 slices (row = 8 uint4), unroll 4, fp32 out ----------------
__global__ __launch_bounds__(256) void gather2_kernel(const unsigned short* __restrict__ g2,
                                                      const unsigned short* __restrict__ esrc,
                                                      const int* __restrict__ off,
                                                      const int* __restrict__ cnt,
                                                      const float* __restrict__ dinv,
                                                      const float* __restrict__ b2,
                                                      float* __restrict__ out) {
    const int slice = blockIdx.x & 1;
    const int n = (blockIdx.x >> 1) * 64 + (threadIdx.x >> 2);
    if (n >= NN) return;
    const int p = threadIdx.x & 3;
    const int col = slice * 4 + p;               // uint4 col in [0,8)
    const uint4* G = (const uint4*)g2;           // row stride 8
    float a0[8] = {0,0,0,0,0,0,0,0};
    float a1[8] = {0,0,0,0,0,0,0,0};
    float a2[8] = {0,0,0,0,0,0,0,0};
    float a3[8] = {0,0,0,0,0,0,0,0};
    addrow(a0, G[(size_t)n * 8 + col]);          // self-loop
    int s0 = off[n], c = cnt[n];
    int i = 0;
    for (; i + 3 < c; i += 4) {
        int sA = esrc[s0 + i];
        int sB = esrc[s0 + i + 1];
        int sC = esrc[s0 + i + 2];
        int sD = esrc[s0 + i + 3];
        uint4 vA = G[(size_t)sA * 8 + col];
        uint4 vB = G[(size_t)sB * 8 + col];
        uint4 vC = G[(size_t)sC * 8 + col];
        uint4 vD = G[(size_t)sD * 8 + col];
        addrow(a0, vA);
        addrow(a1, vB);
        addrow(a2, vC);
        addrow(a3, vD);
    }
    for (; i < c; i++) addrow(a0, G[(size_t)esrc[s0 + i] * 8 + col]);
    #pragma unroll
    for (int j = 0; j < 8; j++) a0[j] += a1[j] + a2[j] + a3[j];
    float sc = dinv[n];
    float4 bA = ((const float4*)b2)[col * 2];
    float4 bB = ((const float4*)b2)[col * 2 + 1];
    float* o = out + (size_t)n * 64 + col * 8;
    *(float4*)o = make_float4(sc * a0[0] + bA.x, sc * a0[1] + bA.y,
                              sc * a0[2] + bA.z, sc * a0[3] + bA.w);
    *(float4*)(o + 4) = make_float4(sc * a0[4] + bB.x, sc * a0[5] + bB.y,
                                    sc * a0[6] + bB.z, sc * a0[7] + bB.w);
}

extern "C" void kernel_launch(void* const* d_in, const int* in_sizes, int n_in,
                              void* d_out, int out_size, void* d_ws, size_t ws_size,
                              hipStream_t stream) {
    const float* x  = (const float*)d_in[0];
    const int* edges = (const int*)d_in[1];     // [2, NE] int32
    const float* W1 = (const float*)d_in[2];
    const float* b1 = (const float*)d_in[3];
    const float* W2 = (const float*)d_in[4];
    const float* b2 = (const float*)d_in[5];
    const int* src = edges;
    const int* dst = edges + NE;

    // workspace layout (all chunks 16B-aligned)
    int* localOff  = (int*)d_ws;                        // NBLK*200 = 78200, pad 78208
    unsigned int* ebuf = (unsigned int*)(localOff + 78208);   // NBLK*EPB = 800768
    unsigned short* esrc = (unsigned short*)(ebuf + (size_t)NBLK * EPB);  // 800000 u16, pad 800768
    int* cnt       = (int*)(esrc + 800768);             // 50048
    int* off       = cnt + 50048;                       // 50048
    float* dinv    = (float*)(off + 50048);             // 50048
    unsigned short* g1 = (unsigned short*)(dinv + 50048);   // [N][128] bf16 row-major
    unsigned short* x2 = g1 + (size_t)NN * C1;              // [N][128] bf16 row-major
    unsigned short* g2 = g1;                            // alias: g1 dead before mm2
    float* out = (float*)d_out;

    bin_kernel<<<NBLK, 256, 0, stream>>>(src, dst, ebuf, localOff);
    place_kernel<<<NBK, 256, 0, stream>>>(ebuf, localOff, esrc, cnt, off, dinv);

    mm1_kernel<<<MMB, 256, 0, stream>>>(x, W1, dinv, g1);
    gather1_kernel<<<GNB * 4, 256, 0, stream>>>(g1, esrc, off, cnt, dinv, b1, x2);

    mm2_kernel<<<MMB, 256, 0, stream>>>(x2, W2, dinv, g2);
    gather2_kernel<<<GNB * 2, 256, 0, stream>>>(g2, esrc, off, cnt, dinv, b2, out);
}

// Round 15
// 183.548 us; speedup vs baseline: 1.0211x; 1.0211x over previous
//
#include <hip/hip_runtime.h>

typedef __attribute__((ext_vector_type(8))) short bf16x8;
typedef __attribute__((ext_vector_type(4))) float f32x4;

constexpr int NN = 50000;          // nodes
constexpr int NE = 800000;         // edges
constexpr int C1 = 128;            // in/hidden channels
constexpr int C2 = 64;             // out channels
constexpr int NBK = 196;           // dst buckets of 256 nodes
constexpr int EPB = 2048;          // edges per bin block
constexpr int NBLK = (NE + EPB - 1) / EPB;   // 391
constexpr int MT = NN / 16;        // 3125 M-tiles (exact)
constexpr int MMB = 500;           // matmul blocks: 2 blocks/CU -> 8 waves/CU latency hiding
constexpr int MMWAVES = MMB * 4;   // 2000 waves
constexpr int CAP = 8192;          // LDS edge cache per bucket
constexpr int GNB = (NN + 63) / 64;   // 782 gather node-blocks (64 nodes each)

// float -> bf16 round-to-nearest-even
__device__ __forceinline__ unsigned short f2bf(float f) {
    unsigned int u = __float_as_uint(f);
    u += 0x7FFFu + ((u >> 16) & 1u);
    return (unsigned short)(u >> 16);
}
// packed bf16 pair -> two floats (low ushort = even element)
__device__ __forceinline__ float2 bf2f(unsigned int u) {
    return make_float2(__uint_as_float(u << 16), __uint_as_float(u & 0xFFFF0000u));
}
__device__ __forceinline__ bf16x8 pack8(float4 a, float4 b) {
    bf16x8 r;
    r[0] = (short)f2bf(a.x); r[1] = (short)f2bf(a.y);
    r[2] = (short)f2bf(a.z); r[3] = (short)f2bf(a.w);
    r[4] = (short)f2bf(b.x); r[5] = (short)f2bf(b.y);
    r[6] = (short)f2bf(b.z); r[7] = (short)f2bf(b.w);
    return r;
}
// accumulate 8 packed bf16 (uint4) into 8 fp32
__device__ __forceinline__ void addrow(float* a, uint4 v) {
    float2 p;
    p = bf2f(v.x); a[0] += p.x; a[1] += p.y;
    p = bf2f(v.y); a[2] += p.x; a[3] += p.y;
    p = bf2f(v.z); a[4] += p.x; a[5] += p.y;
    p = bf2f(v.w); a[6] += p.x; a[7] += p.y;
}

// ---------------- CSR build pass 1: per-block counting sort by coarse bucket ----------------
__global__ __launch_bounds__(256) void bin_kernel(const int* __restrict__ src,
                                                  const int* __restrict__ dst,
                                                  unsigned int* __restrict__ ebuf,
                                                  int* __restrict__ localOff) {
    __shared__ int lhist[NBK];
    __shared__ int ls[256];
    __shared__ int lcur[NBK];
    __shared__ unsigned int lbuf[EPB];
    const int t = threadIdx.x;
    const int base = blockIdx.x * EPB;
    if (t < NBK) lhist[t] = 0;
    __syncthreads();
    int b[8]; unsigned int p[8];
    #pragma unroll
    for (int i = 0; i < 8; i++) {
        int e = base + i * 256 + t;
        if (e < NE) {
            int s = src[e], d = dst[e];
            b[i] = d >> 8;
            p[i] = ((unsigned int)(d & 255) << 16) | (unsigned int)s;
            atomicAdd(&lhist[b[i]], 1);
        } else b[i] = -1;
    }
    __syncthreads();
    int v = (t < NBK) ? lhist[t] : 0;
    ls[t] = v;
    __syncthreads();
    #pragma unroll
    for (int d = 1; d < 256; d <<= 1) {
        int u = (t >= d) ? ls[t - d] : 0;
        __syncthreads();
        ls[t] += u;
        __syncthreads();
    }
    if (t < NBK) {
        lcur[t] = ls[t] - v;
        localOff[blockIdx.x * 200 + t] = ls[t] - v;
    }
    if (t == NBK - 1) localOff[blockIdx.x * 200 + NBK] = ls[t];
    __syncthreads();
    #pragma unroll
    for (int i = 0; i < 8; i++) {
        if (b[i] >= 0) {
            int lp = atomicAdd(&lcur[b[i]], 1);
            lbuf[lp] = p[i];
        }
    }
    __syncthreads();
    #pragma unroll
    for (int i = 0; i < 8; i++)
        ebuf[base + i * 256 + t] = lbuf[i * 256 + t];   // tail garbage never read
}

// ---------------- CSR build pass 2: one block per bucket, bucket edges cached in LDS ---------
__global__ __launch_bounds__(256) void place_kernel(const unsigned int* __restrict__ ebuf,
                                                    const int* __restrict__ localOff,
                                                    unsigned short* __restrict__ esrc,
                                                    int* __restrict__ cnt,
                                                    int* __restrict__ off,
                                                    float* __restrict__ dinv) {
    __shared__ unsigned int lbuf[CAP];   // 32 KB
    __shared__ int lhist[256];
    __shared__ int ls[256];
    __shared__ int lcur[256];
    __shared__ int red[256];
    const int t = threadIdx.x;
    const int bkt = blockIdx.x;
    const int node0 = bkt << 8;
    const int nnodes = min(256, NN - node0);

    const int j0 = 2 * t, j1 = 2 * t + 1;
    int s0 = 0, l0 = 0, s1 = 0, l1 = 0;
    if (j0 < NBLK) { s0 = localOff[j0 * 200 + bkt]; l0 = localOff[j0 * 200 + bkt + 1] - s0; }
    if (j1 < NBLK) { s1 = localOff[j1 * 200 + bkt]; l1 = localOff[j1 * 200 + bkt + 1] - s1; }

    red[t] = s0 + s1;          // -> segBase (sum of chunk-local exclusive prefixes)
    ls[t] = l0 + l1;           // -> lbuf base scan
    lhist[t] = 0;
    __syncthreads();
    #pragma unroll
    for (int d = 1; d < 256; d <<= 1) {
        int u = (t >= d) ? ls[t - d] : 0;
        int r = (t + d < 256) ? red[t + d] : 0;
        __syncthreads();
        ls[t] += u;
        red[t] += r;
        __syncthreads();
    }
    const int segBase = red[0];
    const int total = ls[255];
    const int base0 = ls[t] - (l0 + l1);
    const int base1 = base0 + l0;
    const bool fits = (total <= CAP);

    if (fits) {
        const unsigned int* q0 = ebuf + j0 * EPB + s0;
        for (int k = 0; k < l0; k++) lbuf[base0 + k] = q0[k];
        const unsigned int* q1 = ebuf + j1 * EPB + s1;
        for (int k = 0; k < l1; k++) lbuf[base1 + k] = q1[k];
        __syncthreads();
        for (int k = t; k < total; k += 256) atomicAdd(&lhist[lbuf[k] >> 16], 1);
    } else {
        const unsigned int* q0 = ebuf + j0 * EPB + s0;
        for (int k = 0; k < l0; k++) atomicAdd(&lhist[q0[k] >> 16], 1);
        const unsigned int* q1 = ebuf + j1 * EPB + s1;
        for (int k = 0; k < l1; k++) atomicAdd(&lhist[q1[k] >> 16], 1);
    }
    __syncthreads();
    int v = lhist[t];
    ls[t] = v;
    __syncthreads();
    #pragma unroll
    for (int d = 1; d < 256; d <<= 1) {
        int u = (t >= d) ? ls[t - d] : 0;
        __syncthreads();
        ls[t] += u;
        __syncthreads();
    }
    int ex = ls[t] - v;
    lcur[t] = ex;
    if (t < nnodes) {
        cnt[node0 + t] = v;
        off[node0 + t] = segBase + ex;
        dinv[node0 + t] = rsqrtf((float)v + 1.0f);
    }
    __syncthreads();
    if (fits) {
        for (int k = t; k < total; k += 256) {
            unsigned int pp = lbuf[k];
            int lp = atomicAdd(&lcur[pp >> 16], 1);
            esrc[segBase + lp] = (unsigned short)(pp & 0xFFFFu);
        }
    } else {
        const unsigned int* q0 = ebuf + j0 * EPB + s0;
        for (int k = 0; k < l0; k++) {
            unsigned int pp = q0[k];
            int lp = atomicAdd(&lcur[pp >> 16], 1);
            esrc[segBase + lp] = (unsigned short)(pp & 0xFFFFu);
        }
        const unsigned int* q1 = ebuf + j1 * EPB + s1;
        for (int k = 0; k < l1; k++) {
            unsigned int pp = q1[k];
            int lp = atomicAdd(&lcur[pp >> 16], 1);
            esrc[segBase + lp] = (unsigned short)(pp & 0xFFFFu);
        }
    }
}

// ---------------- mm1: g1(bf16, row-major) = dinv * (x @ W1) via MFMA 16x16x32 bf16 ----------
__global__ __launch_bounds__(256, 2) void mm1_kernel(const float* __restrict__ x,
                                                     const float* __restrict__ W,
                                                     const float* __restrict__ dinv,
                                                     unsigned short* __restrict__ g1) {
    __shared__ unsigned short wl[4][8][64][8];   // 32 KB, B-fragment order
    const int t = threadIdx.x;
    for (int i = 0; i < 64; i++) {
        int idx = i * 256 + t;
        int k = idx >> 7, n = idx & 127;
        wl[k >> 5][n >> 4][((k >> 3) & 3) * 16 + (n & 15)][k & 7] = f2bf(W[idx]);
    }
    __syncthreads();
    const int lane = t & 63, lm = lane & 15, quad = lane >> 4;

    bf16x8 bfr[4][8];
    #pragma unroll
    for (int s = 0; s < 4; s++)
        #pragma unroll
        for (int nt = 0; nt < 8; nt++)
            bfr[s][nt] = *(const bf16x8*)&wl[s][nt][lane][0];

    int wg = blockIdx.x * 4 + (t >> 6);
    for (int tile = wg; tile < MT; tile += MMWAVES) {
        int row0 = tile << 4;
        const float* xr = x + (size_t)(row0 + lm) * 128 + quad * 8;
        bf16x8 af[4];
        #pragma unroll
        for (int s = 0; s < 4; s++) {
            float4 p = *(const float4*)(xr + s * 32);
            float4 q = *(const float4*)(xr + s * 32 + 4);
            af[s] = pack8(p, q);
        }
        f32x4 acc[8];
        #pragma unroll
        for (int nt = 0; nt < 8; nt++) acc[nt] = (f32x4){0.f, 0.f, 0.f, 0.f};
        #pragma unroll
        for (int s = 0; s < 4; s++)
            #pragma unroll
            for (int nt = 0; nt < 8; nt++)
                acc[nt] = __builtin_amdgcn_mfma_f32_16x16x32_bf16(af[s], bfr[s][nt],
                                                                  acc[nt], 0, 0, 0);
        float4 dv = *(const float4*)(dinv + row0 + quad * 4);
        float dvv[4] = {dv.x, dv.y, dv.z, dv.w};
        #pragma unroll
        for (int nt = 0; nt < 8; nt++)
            #pragma unroll
            for (int r = 0; r < 4; r++)
                g1[(size_t)(row0 + quad * 4 + r) * 128 + nt * 16 + lm] =
                    f2bf(acc[nt][r] * dvv[r]);
    }
}

// ---------------- mm2: g2(bf16, row-major) = dinv * (x2 @ W2), x2 already bf16 ---------------
__global__ __launch_bounds__(256, 2) void mm2_kernel(const unsigned short* __restrict__ x2,
                                                     const float* __restrict__ W,
                                                     const float* __restrict__ dinv,
                                                     unsigned short* __restrict__ g2) {
    __shared__ unsigned short wl[4][4][64][8];   // 16 KB
    const int t = threadIdx.x;
    for (int i = 0; i < 32; i++) {
        int idx = i * 256 + t;
        int k = idx >> 6, n = idx & 63;
        wl[k >> 5][n >> 4][((k >> 3) & 3) * 16 + (n & 15)][k & 7] = f2bf(W[idx]);
    }
    __syncthreads();
    const int lane = t & 63, lm = lane & 15, quad = lane >> 4;

    bf16x8 bfr[4][4];
    #pragma unroll
    for (int s = 0; s < 4; s++)
        #pragma unroll
        for (int nt = 0; nt < 4; nt++)
            bfr[s][nt] = *(const bf16x8*)&wl[s][nt][lane][0];

    int wg = blockIdx.x * 4 + (t >> 6);
    for (int tile = wg; tile < MT; tile += MMWAVES) {
        int row0 = tile << 4;
        const bf16x8* xr = (const bf16x8*)(x2 + (size_t)(row0 + lm) * 128 + quad * 8);
        bf16x8 af[4];
        #pragma unroll
        for (int s = 0; s < 4; s++) af[s] = xr[s * 4];
        f32x4 acc[4];
        #pragma unroll
        for (int nt = 0; nt < 4; nt++) acc[nt] = (f32x4){0.f, 0.f, 0.f, 0.f};
        #pragma unroll
        for (int s = 0; s < 4; s++)
            #pragma unroll
            for (int nt = 0; nt < 4; nt++)
                acc[nt] = __builtin_amdgcn_mfma_f32_16x16x32_bf16(af[s], bfr[s][nt],
                                                                  acc[nt], 0, 0, 0);
        float4 dv = *(const float4*)(dinv + row0 + quad * 4);
        float dvv[4] = {dv.x, dv.y, dv.z, dv.w};
        #pragma unroll
        for (int nt = 0; nt < 4; nt++)
            #pragma unroll
            for (int r = 0; r < 4; r++)
                g2[(size_t)(row0 + quad * 4 + r) * 64 + nt * 16 + lm] =
                    f2bf(acc[nt][r] * dvv[r]);
    }
}

// ---------------- gather1: XCD-pinned 64B slice, 4-lane group x uint4, unroll 2 (R13 best) ---
// Row = 16 uint4. Group = 4 lanes, each owns one uint4 (8 ch); group owns (node, slice).
// slice = blockIdx&3 (b%8 XCD round-robin -> XCD x only touches slice x&3, 3.2 MB resident).
__global__ __launch_bounds__(256) void gather1_kernel(const unsigned short* __restrict__ g1,
                                                      const unsigned short* __restrict__ esrc,
                                                      const int* __restrict__ off,
                                                      const int* __restrict__ cnt,
                                                      const float* __restrict__ dinv,
                                                      const float* __restrict__ b1,
                                                      unsigned short* __restrict__ x2) {
    const int slice = blockIdx.x & 3;
    const int n = (blockIdx.x >> 2) * 64 + (threadIdx.x >> 2);
    if (n >= NN) return;
    const int p = threadIdx.x & 3;
    const int col = slice * 4 + p;               // uint4 col in [0,16)
    const uint4* G = (const uint4*)g1;           // row stride 16
    float a0[8] = {0,0,0,0,0,0,0,0};
    float a1[8] = {0,0,0,0,0,0,0,0};
    addrow(a0, G[(size_t)n * 16 + col]);         // self-loop (lane owns its 8 ch)
    int s0 = off[n], c = cnt[n];
    int i = 0;
    for (; i + 1 < c; i += 2) {
        int sA = esrc[s0 + i];
        int sB = esrc[s0 + i + 1];
        uint4 vA = G[(size_t)sA * 16 + col];
        uint4 vB = G[(size_t)sB * 16 + col];
        addrow(a0, vA);
        addrow(a1, vB);
    }
    if (i < c) addrow(a0, G[(size_t)esrc[s0 + i] * 16 + col]);
    #pragma unroll
    for (int j = 0; j < 8; j++) a0[j] += a1[j];
    float sc = dinv[n];
    float4 bA = ((const float4*)b1)[col * 2];
    float4 bB = ((const float4*)b1)[col * 2 + 1];
    float4 pp = make_float4(fmaxf(sc * a0[0] + bA.x, 0.f), fmaxf(sc * a0[1] + bA.y, 0.f),
                            fmaxf(sc * a0[2] + bA.z, 0.f), fmaxf(sc * a0[3] + bA.w, 0.f));
    float4 qq = make_float4(fmaxf(sc * a0[4] + bB.x, 0.f), fmaxf(sc * a0[5] + bB.y, 0.f),
                            fmaxf(sc * a0[6] + bB.z, 0.f), fmaxf(sc * a0[7] + bB.w, 0.f));
    *(bf16x8*)(x2 + (size_t)n * 128 + col * 8) = pack8(pp, qq);
}

// ---------------- gather2: same, 2 slices (row = 8 uint4), unroll 2, fp32 out ----------------
__global__ __launch_bounds__(256) void gather2_kernel(const unsigned short* __restrict__ g2,
                                                      const unsigned short* __restrict__ esrc,
                                                      const int* __restrict__ off,
                                                      const int* __restrict__ cnt,
                                                      const float* __restrict__ dinv,
                                                      const float* __restrict__ b2,
                                                      float* __restrict__ out) {
    const int slice = blockIdx.x & 1;
    const int n = (blockIdx.x >> 1) * 64 + (threadIdx.x >> 2);
    if (n >= NN) return;
    const int p = threadIdx.x & 3;
    const int col = slice * 4 + p;               // uint4 col in [0,8)
    const uint4* G = (const uint4*)g2;           // row stride 8
    float a0[8] = {0,0,0,0,0,0,0,0};
    float a1[8] = {0,0,0,0,0,0,0,0};
    addrow(a0, G[(size_t)n * 8 + col]);          // self-loop
    int s0 = off[n], c = cnt[n];
    int i = 0;
    for (; i + 1 < c; i += 2) {
        int sA = esrc[s0 + i];
        int sB = esrc[s0 + i + 1];
        uint4 vA = G[(size_t)sA * 8 + col];
        uint4 vB = G[(size_t)sB * 8 + col];
        addrow(a0, vA);
        addrow(a1, vB);
    }
    if (i < c) addrow(a0, G[(size_t)esrc[s0 + i] * 8 + col]);
    #pragma unroll
    for (int j = 0; j < 8; j++) a0[j] += a1[j];
    float sc = dinv[n];
    float4 bA = ((const float4*)b2)[col * 2];
    float4 bB = ((const float4*)b2)[col * 2 + 1];
    float* o = out + (size_t)n * 64 + col * 8;
    *(float4*)o = make_float4(sc * a0[0] + bA.x, sc * a0[1] + bA.y,
                              sc * a0[2] + bA.z, sc * a0[3] + bA.w);
    *(float4*)(o + 4) = make_float4(sc * a0[4] + bB.x, sc * a0[5] + bB.y,
                                    sc * a0[6] + bB.z, sc * a0[7] + bB.w);
}

extern "C" void kernel_launch(void* const* d_in, const int* in_sizes, int n_in,
                              void* d_out, int out_size, void* d_ws, size_t ws_size,
                              hipStream_t stream) {
    const float* x  = (const float*)d_in[0];
    const int* edges = (const int*)d_in[1];     // [2, NE] int32
    const float* W1 = (const float*)d_in[2];
    const float* b1 = (const float*)d_in[3];
    const float* W2 = (const float*)d_in[4];
    const float* b2 = (const float*)d_in[5];
    const int* src = edges;
    const int* dst = edges + NE;

    // workspace layout (all chunks 16B-aligned)
    int* localOff  = (int*)d_ws;                        // NBLK*200 = 78200, pad 78208
    unsigned int* ebuf = (unsigned int*)(localOff + 78208);   // NBLK*EPB = 800768
    unsigned short* esrc = (unsigned short*)(ebuf + (size_t)NBLK * EPB);  // 800000 u16, pad 800768
    int* cnt       = (int*)(esrc + 800768);             // 50048
    int* off       = cnt + 50048;                       // 50048
    float* dinv    = (float*)(off + 50048);             // 50048
    unsigned short* g1 = (unsigned short*)(dinv + 50048);   // [N][128] bf16 row-major
    unsigned short* x2 = g1 + (size_t)NN * C1;              // [N][128] bf16 row-major
    unsigned short* g2 = g1;                            // alias: g1 dead before mm2
    float* out = (float*)d_out;

    bin_kernel<<<NBLK, 256, 0, stream>>>(src, dst, ebuf, localOff);
    place_kernel<<<NBK, 256, 0, stream>>>(ebuf, localOff, esrc, cnt, off, dinv);

    mm1_kernel<<<MMB, 256, 0, stream>>>(x, W1, dinv, g1);
    gather1_kernel<<<GNB * 4, 256, 0, stream>>>(g1, esrc, off, cnt, dinv, b1, x2);

    mm2_kernel<<<MMB, 256, 0, stream>>>(x2, W2, dinv, g2);
    gather2_kernel<<<GNB * 2, 256, 0, stream>>>(g2, esrc, off, cnt, dinv, b2, out);
}